// Round 1
// baseline (330.471 us; speedup 1.0000x reference)
//
#include <hip/hip_runtime.h>
#include <stdint.h>

typedef __attribute__((ext_vector_type(4))) float f32x4;
typedef __attribute__((ext_vector_type(8))) short bf16x8;
typedef unsigned short u16;
typedef unsigned int u32;

#define DEVINL __device__ __forceinline__

DEVINL u16 f2bf(float f) {
  u32 u = __builtin_bit_cast(u32, f);
  u += 0x7FFFu + ((u >> 16) & 1u);
  return (u16)(u >> 16);
}

DEVINL void gload16(const void* g, void* l) {
  __builtin_amdgcn_global_load_lds((const __attribute__((address_space(1))) void*)g,
                                   (__attribute__((address_space(3))) void*)l, 16, 0, 0);
}

// ---------------- fp32 -> bf16 convert (vectorized) ----------------
__global__ void cvt_bf16(const float* __restrict__ in, u16* __restrict__ out, int n4) {
  int i = blockIdx.x * blockDim.x + threadIdx.x;
  if (i >= n4) return;
  float4 v = ((const float4*)in)[i];
  ushort4 o;
  o.x = f2bf(v.x); o.y = f2bf(v.y); o.z = f2bf(v.z); o.w = f2bf(v.w);
  ((ushort4*)out)[i] = o;
}

// ---------------- mask dtype detect + canonicalize to u8 ----------------
// bool may arrive as u8 bytes, int32 {0,1}, or float32 {0,1.0}. Detect:
// first 1024 words all in {0,1} -> int32; all in {0,0x3f800000} -> f32; else bytes.
__global__ void mask_prep(const u32* __restrict__ mraw, unsigned char* __restrict__ mout) {
  __shared__ int notint, notfloat;
  int tid = threadIdx.x;
  if (tid == 0) { notint = 0; notfloat = 0; }
  __syncthreads();
  u32 w = mraw[tid];  // 1024 words = 4096 bytes, safe in all interpretations
  if (w != 0u && w != 1u) notint = 1;
  if (w != 0u && w != 0x3f800000u) notfloat = 1;
  __syncthreads();
  bool words = (!notint) || (!notfloat);
  for (int i = tid; i < 4096; i += 1024) {
    u32 v = words ? mraw[i] : (u32)(((const unsigned char*)mraw)[i]);
    mout[i] = v ? 1 : 0;
  }
}

// ---------------- bf16 GEMM, Y = A(MxK) * W(NxK)^T + bias ----------------
// m97 structure: 128x128 tile, BK=32, 4 waves, 4x4 16x16x32 frags/wave.
// mode 0: write bf16 [B][H][T][64]   (rows r=t*2+b, cols j=h*64+dh)
// mode 2: write bf16 [B][H][64][T]   (V transposed)
// mode 3: write fp32 out[(t*2+b)*1024 + j]  (rows r=b*2048+t)
__global__ __launch_bounds__(256) void gemm_bt(
    const u16* __restrict__ A, const u16* __restrict__ W, const float* __restrict__ bias,
    u16* __restrict__ out_bf, float* __restrict__ out_f, int M, int N, int K, int mode) {
  __shared__ u16 As[128 * 32];
  __shared__ u16 Bs[128 * 32];
  const int tid = threadIdx.x, lane = tid & 63;
  const int wave = tid >> 6, wm = wave & 1, wn = wave >> 1;
  const int tiles_n = N >> 7;
  const int m0 = (blockIdx.x / tiles_n) << 7;
  const int n0 = (blockIdx.x % tiles_n) << 7;
  const int l15 = lane & 15, l4 = lane >> 4;
  const f32x4 zero = {0.f, 0.f, 0.f, 0.f};
  f32x4 acc[4][4];
#pragma unroll
  for (int i = 0; i < 4; i++)
#pragma unroll
    for (int j = 0; j < 4; j++) acc[i][j] = zero;

  for (int kt = 0; kt < K; kt += 32) {
#pragma unroll
    for (int it = 0; it < 2; ++it) {
      int c = tid + (it << 8);
      int row = c >> 2, q = c & 3;
      gload16(A + (size_t)(m0 + row) * K + kt + q * 8, (void*)(As + c * 8));
      gload16(W + (size_t)(n0 + row) * K + kt + q * 8, (void*)(Bs + c * 8));
    }
    __syncthreads();
    bf16x8 af[4], bfr[4];
#pragma unroll
    for (int i = 0; i < 4; i++) {
      af[i]  = *(const bf16x8*)(As + ((wm << 6) + (i << 4) + l15) * 32 + l4 * 8);
      bfr[i] = *(const bf16x8*)(Bs + ((wn << 6) + (i << 4) + l15) * 32 + l4 * 8);
    }
#pragma unroll
    for (int i = 0; i < 4; i++)
#pragma unroll
      for (int j = 0; j < 4; j++)
        acc[i][j] = __builtin_amdgcn_mfma_f32_16x16x32_bf16(af[i], bfr[j], acc[i][j], 0, 0, 0);
    __syncthreads();
  }

#pragma unroll
  for (int j = 0; j < 4; j++) {
    const int col = n0 + (wn << 6) + (j << 4) + l15;
    const float bc = bias[col];
#pragma unroll
    for (int i = 0; i < 4; i++) {
#pragma unroll
      for (int r = 0; r < 4; r++) {
        const int row = m0 + (wm << 6) + (i << 4) + (l4 << 2) + r;
        float v = acc[i][j][r] + bc;
        if (mode == 3) {
          int t = row & 2047, b2 = row >> 11;
          out_f[(size_t)(t * 2 + b2) * 1024 + col] = v;
        } else {
          int t = row >> 1, b2 = row & 1, h = col >> 6, dh = col & 63;
          if (mode == 2)
            out_bf[((size_t)(b2 * 16 + h) * 64 + dh) * 2048 + t] = f2bf(v);
          else
            out_bf[((size_t)(b2 * 16 + h) * 2048 + t) * 64 + dh] = f2bf(v);
        }
      }
    }
  }
}

// ---------------- flash attention ----------------
// grid: 512 blocks = 32 (b,h) x 16 q-tiles of 128. 4 waves, each owns 32 q rows.
// Q [bh][2048][64] bf16, K [bh][2048][64] bf16, Vt [bh][64][2048] bf16.
// ctx out: [b][t][h*64+d] bf16.
__global__ __launch_bounds__(256) void attn_fwd(
    const u16* __restrict__ Qh, const u16* __restrict__ Kh, const u16* __restrict__ Vt,
    const unsigned char* __restrict__ maskb, u16* __restrict__ ctx) {
  __shared__ u16 Ks[64 * 64];
  __shared__ u16 Vs[64 * 64];
  __shared__ u16 Pl[4][32 * 64];
  const int tid = threadIdx.x, lane = tid & 63, wave = tid >> 6;
  const int qt = blockIdx.x & 15, bh = blockIdx.x >> 4;
  const int bb = bh >> 4, h = bh & 15;
  const int l15 = lane & 15, l4 = lane >> 4;
  const f32x4 zero = {0.f, 0.f, 0.f, 0.f};

  // Q fragments, held for whole kernel
  bf16x8 qf[2][2];
#pragma unroll
  for (int mi = 0; mi < 2; mi++)
#pragma unroll
    for (int kb = 0; kb < 2; kb++)
      qf[mi][kb] = *(const bf16x8*)(Qh + ((size_t)bh * 2048 + qt * 128 + wave * 32 + mi * 16 + l15) * 64 + kb * 32 + l4 * 8);

  f32x4 O[2][4];
  float m_[2][4], l_[2][4];
#pragma unroll
  for (int mi = 0; mi < 2; mi++) {
#pragma unroll
    for (int nd = 0; nd < 4; nd++) O[mi][nd] = zero;
#pragma unroll
    for (int r = 0; r < 4; r++) { m_[mi][r] = -1e30f; l_[mi][r] = 0.f; }
  }

  for (int kt = 0; kt < 32; ++kt) {
    // stage K tile [64 j][64 d] and Vt tile [64 d][64 j] to LDS
#pragma unroll
    for (int it = 0; it < 2; ++it) {
      int c = tid + (it << 8);
      int rr = c >> 3, qq = c & 7;
      gload16(Kh + ((size_t)bh * 2048 + kt * 64 + rr) * 64 + qq * 8, (void*)(Ks + c * 8));
      gload16(Vt + ((size_t)bh * 64 + rr) * 2048 + kt * 64 + qq * 8, (void*)(Vs + c * 8));
    }
    __syncthreads();

    // S = Q K^T
    f32x4 s[2][4];
#pragma unroll
    for (int mi = 0; mi < 2; mi++)
#pragma unroll
      for (int ni = 0; ni < 4; ni++) s[mi][ni] = zero;
#pragma unroll
    for (int ni = 0; ni < 4; ni++) {
#pragma unroll
      for (int kb = 0; kb < 2; kb++) {
        bf16x8 kf = *(const bf16x8*)(Ks + (ni * 16 + l15) * 64 + kb * 32 + l4 * 8);
        s[0][ni] = __builtin_amdgcn_mfma_f32_16x16x32_bf16(qf[0][kb], kf, s[0][ni], 0, 0, 0);
        s[1][ni] = __builtin_amdgcn_mfma_f32_16x16x32_bf16(qf[1][kb], kf, s[1][ni], 0, 0, 0);
      }
    }

    // scale + key-padding mask (masked -> -3e38, finite to avoid NaN)
    float msk[4];
#pragma unroll
    for (int ni = 0; ni < 4; ni++)
      msk[ni] = maskb[bb * 2048 + kt * 64 + ni * 16 + l15] ? -3.0e38f : 0.0f;
#pragma unroll
    for (int mi = 0; mi < 2; mi++)
#pragma unroll
      for (int ni = 0; ni < 4; ni++)
#pragma unroll
        for (int r = 0; r < 4; r++)
          s[mi][ni][r] = s[mi][ni][r] * 0.125f + msk[ni];

    // online softmax per mi-fragment (rows = l4*4+r, distributed over 16 lanes)
#pragma unroll
    for (int mi = 0; mi < 2; mi++) {
      float pm[4];
#pragma unroll
      for (int r = 0; r < 4; r++)
        pm[r] = fmaxf(fmaxf(s[mi][0][r], s[mi][1][r]), fmaxf(s[mi][2][r], s[mi][3][r]));
#pragma unroll
      for (int off = 1; off < 16; off <<= 1)
#pragma unroll
        for (int r = 0; r < 4; r++) pm[r] = fmaxf(pm[r], __shfl_xor(pm[r], off));
      float al[4];
#pragma unroll
      for (int r = 0; r < 4; r++) {
        float mn = fmaxf(m_[mi][r], pm[r]);
        al[r] = __expf(m_[mi][r] - mn);
        m_[mi][r] = mn;
      }
      float rs[4] = {0.f, 0.f, 0.f, 0.f};
#pragma unroll
      for (int ni = 0; ni < 4; ni++)
#pragma unroll
        for (int r = 0; r < 4; r++) {
          float p = __expf(s[mi][ni][r] - m_[mi][r]);
          s[mi][ni][r] = p;
          rs[r] += p;
        }
#pragma unroll
      for (int off = 1; off < 16; off <<= 1)
#pragma unroll
        for (int r = 0; r < 4; r++) rs[r] += __shfl_xor(rs[r], off);
#pragma unroll
      for (int r = 0; r < 4; r++) l_[mi][r] = l_[mi][r] * al[r] + rs[r];
#pragma unroll
      for (int nd = 0; nd < 4; nd++)
#pragma unroll
        for (int r = 0; r < 4; r++) O[mi][nd][r] *= al[r];
      // P -> LDS (bf16), transposing C-layout to A-fragment layout
#pragma unroll
      for (int ni = 0; ni < 4; ni++)
#pragma unroll
        for (int r = 0; r < 4; r++)
          Pl[wave][(mi * 16 + l4 * 4 + r) * 64 + ni * 16 + l15] = f2bf(s[mi][ni][r]);
    }

    // O += P V  (A-frags from Pl, B-frags from Vs; per-wave LDS, in-order DS pipe)
    bf16x8 pa[2][2];
#pragma unroll
    for (int mi = 0; mi < 2; mi++)
#pragma unroll
      for (int jb = 0; jb < 2; jb++)
        pa[mi][jb] = *(const bf16x8*)(&Pl[wave][(mi * 16 + l15) * 64 + jb * 32 + l4 * 8]);
#pragma unroll
    for (int nd = 0; nd < 4; nd++) {
#pragma unroll
      for (int jb = 0; jb < 2; jb++) {
        bf16x8 vf = *(const bf16x8*)(Vs + (nd * 16 + l15) * 64 + jb * 32 + l4 * 8);
        O[0][nd] = __builtin_amdgcn_mfma_f32_16x16x32_bf16(pa[0][jb], vf, O[0][nd], 0, 0, 0);
        O[1][nd] = __builtin_amdgcn_mfma_f32_16x16x32_bf16(pa[1][jb], vf, O[1][nd], 0, 0, 0);
      }
    }
    __syncthreads();
  }

  // normalize + write ctx[b][t][h*64+d]
#pragma unroll
  for (int mi = 0; mi < 2; mi++) {
#pragma unroll
    for (int r = 0; r < 4; r++) {
      float li = l_[mi][r];
      float inv = (li > 0.f) ? 1.0f / li : 0.f;
      int t = qt * 128 + wave * 32 + mi * 16 + l4 * 4 + r;
#pragma unroll
      for (int nd = 0; nd < 4; nd++) {
        int d = nd * 16 + l15;
        ctx[((size_t)bb * 2048 + t) * 1024 + h * 64 + d] = f2bf(O[mi][nd][r] * inv);
      }
    }
  }
}

// ---------------- host ----------------
extern "C" void kernel_launch(void* const* d_in, const int* in_sizes, int n_in,
                              void* d_out, int out_size, void* d_ws, size_t ws_size,
                              hipStream_t stream) {
  const float* q_in = (const float*)d_in[0];
  const float* k_in = (const float*)d_in[1];
  const float* v_in = (const float*)d_in[2];
  const float* Wq = (const float*)d_in[3];
  const float* bq = (const float*)d_in[4];
  const float* Wk = (const float*)d_in[5];
  const float* bk = (const float*)d_in[6];
  const float* Wv = (const float*)d_in[7];
  const float* bv = (const float*)d_in[8];
  const float* Wo = (const float*)d_in[9];
  const float* bo = (const float*)d_in[10];
  const void* mask = d_in[11];

  const size_t SZ_X = (size_t)4194304 * 2;   // T*B*C bf16 bytes
  const size_t SZ_W = (size_t)1048576 * 2;   // C*C bf16 bytes
  uint8_t* ws = (uint8_t*)d_ws;
  unsigned char* mb = ws + 0;
  size_t off = 8192;
  u16* qbf = (u16*)(ws + off); off += SZ_X;
  u16* kbf = (u16*)(ws + off); off += SZ_X;
  u16* vbf = (u16*)(ws + off); off += SZ_X;
  u16* wqb = (u16*)(ws + off); off += SZ_W;
  u16* wkb = (u16*)(ws + off); off += SZ_W;
  u16* wvb = (u16*)(ws + off); off += SZ_W;
  u16* wob = (u16*)(ws + off); off += SZ_W;
  u16* Qh  = (u16*)(ws + off); off += SZ_X;
  u16* Kh  = (u16*)(ws + off); off += SZ_X;
  u16* Vth = (u16*)(ws + off); off += SZ_X;
  u16* ctx = (u16*)(ws + off); off += SZ_X;
  if (ws_size < off) return;  // workspace too small; fail loudly via wrong output

  mask_prep<<<1, 1024, 0, stream>>>((const u32*)mask, mb);
  cvt_bf16<<<4096, 256, 0, stream>>>(q_in, qbf, 1048576);
  cvt_bf16<<<4096, 256, 0, stream>>>(k_in, kbf, 1048576);
  cvt_bf16<<<4096, 256, 0, stream>>>(v_in, vbf, 1048576);
  cvt_bf16<<<1024, 256, 0, stream>>>(Wq, wqb, 262144);
  cvt_bf16<<<1024, 256, 0, stream>>>(Wk, wkb, 262144);
  cvt_bf16<<<1024, 256, 0, stream>>>(Wv, wvb, 262144);
  cvt_bf16<<<1024, 256, 0, stream>>>(Wo, wob, 262144);

  gemm_bt<<<256, 256, 0, stream>>>(qbf, wqb, bq, Qh, nullptr, 4096, 1024, 1024, 0);
  gemm_bt<<<256, 256, 0, stream>>>(kbf, wkb, bk, Kh, nullptr, 4096, 1024, 1024, 0);
  gemm_bt<<<256, 256, 0, stream>>>(vbf, wvb, bv, Vth, nullptr, 4096, 1024, 1024, 2);

  attn_fwd<<<512, 256, 0, stream>>>(Qh, Kh, Vth, mb, ctx);

  gemm_bt<<<256, 256, 0, stream>>>(ctx, wob, bo, nullptr, (float*)d_out, 4096, 1024, 1024, 3);
}

// Round 2
// 193.077 us; speedup vs baseline: 1.7116x; 1.7116x over previous
//
#include <hip/hip_runtime.h>
#include <stdint.h>

typedef __attribute__((ext_vector_type(4))) float f32x4;
typedef __attribute__((ext_vector_type(8))) short bf16x8;
typedef unsigned short u16;
typedef unsigned int u32;

#define DEVINL __device__ __forceinline__

DEVINL u16 f2bf(float f) {
  u32 u = __builtin_bit_cast(u32, f);
  u += 0x7FFFu + ((u >> 16) & 1u);
  return (u16)(u >> 16);
}

DEVINL void gload16(const void* g, void* l) {
  __builtin_amdgcn_global_load_lds((const __attribute__((address_space(1))) void*)g,
                                   (__attribute__((address_space(3))) void*)l, 16, 0, 0);
}

// ---------------- fused fp32 -> bf16 convert (q,k,v,Wq,Wk,Wv,Wo) ----------------
// dst is the contiguous ws region [q|k|v|wq|wk|wv|wo] in that order.
__global__ void cvt_all(const float* __restrict__ q, const float* __restrict__ k,
                        const float* __restrict__ v, const float* __restrict__ wq,
                        const float* __restrict__ wk, const float* __restrict__ wv,
                        const float* __restrict__ wo, ushort4* __restrict__ dst) {
  int i = blockIdx.x * 256 + threadIdx.x;  // float4 index, total 4194304
  float4 v4;
  if (i < 1048576) v4 = ((const float4*)q)[i];
  else if (i < 2097152) v4 = ((const float4*)k)[i - 1048576];
  else if (i < 3145728) v4 = ((const float4*)v)[i - 2097152];
  else {
    int j = i - 3145728;
    if (j < 262144) v4 = ((const float4*)wq)[j];
    else if (j < 524288) v4 = ((const float4*)wk)[j - 262144];
    else if (j < 786432) v4 = ((const float4*)wv)[j - 524288];
    else v4 = ((const float4*)wo)[j - 786432];
  }
  ushort4 o;
  o.x = f2bf(v4.x); o.y = f2bf(v4.y); o.z = f2bf(v4.z); o.w = f2bf(v4.w);
  dst[i] = o;
}

// ---------------- mask dtype detect + canonicalize to u8 ----------------
__global__ void mask_prep(const u32* __restrict__ mraw, unsigned char* __restrict__ mout) {
  __shared__ int notint, notfloat;
  int tid = threadIdx.x;
  if (tid == 0) { notint = 0; notfloat = 0; }
  __syncthreads();
  u32 w = mraw[tid];
  if (w != 0u && w != 1u) notint = 1;
  if (w != 0u && w != 0x3f800000u) notfloat = 1;
  __syncthreads();
  bool words = (!notint) || (!notfloat);
  for (int i = tid; i < 4096; i += 1024) {
    u32 v = words ? mraw[i] : (u32)(((const unsigned char*)mraw)[i]);
    mout[i] = v ? 1 : 0;
  }
}

// ---------------- bf16 GEMM body, Y = A(4096xK) * W(1024xK)^T + bias ----------------
// 128x128 tile, BK=32, 4 waves, 4x4 16x16x32 frags/wave.
// LDS swizzle: chunk q (16B units, 4/row) ^= (row&3)^((row>>2)&3)  -> 2-way max on reads.
// mode 0: bf16 [B][H][T][64]; mode 2: bf16 [B][H][64][T]; mode 3: fp32 (t*2+b)*1024+col.
DEVINL void gemm_body(const u16* __restrict__ A, const u16* __restrict__ W,
                      const float* __restrict__ bias, u16* __restrict__ out_bf,
                      float* __restrict__ out_f, int tile, int mode,
                      u16* As, u16* Bs) {
  const int tid = threadIdx.x, lane = tid & 63;
  const int wave = tid >> 6, wm = wave & 1, wn = wave >> 1;
  const int m0 = (tile >> 3) << 7;  // tiles_n = 8
  const int n0 = (tile & 7) << 7;
  const int l15 = lane & 15, l4 = lane >> 4;
  const int K = 1024;
  const f32x4 zero = {0.f, 0.f, 0.f, 0.f};
  f32x4 acc[4][4];
#pragma unroll
  for (int i = 0; i < 4; i++)
#pragma unroll
    for (int j = 0; j < 4; j++) acc[i][j] = zero;

  for (int kt = 0; kt < 1024; kt += 32) {
#pragma unroll
    for (int it = 0; it < 2; ++it) {
      int c = tid + (it << 8);
      int row = c >> 2, qs = (c & 3) ^ ((row & 3) ^ ((row >> 2) & 3));
      gload16(A + (size_t)(m0 + row) * K + kt + qs * 8, (void*)(As + c * 8));
      gload16(W + (size_t)(n0 + row) * K + kt + qs * 8, (void*)(Bs + c * 8));
    }
    __syncthreads();
    bf16x8 af[4], bfr[4];
#pragma unroll
    for (int i = 0; i < 4; i++) {
      int ra = (wm << 6) + (i << 4) + l15;
      int rb = (wn << 6) + (i << 4) + l15;
      af[i]  = *(const bf16x8*)(As + ra * 32 + ((l4 * 8) ^ ((((ra & 3) ^ ((ra >> 2) & 3))) << 3)));
      bfr[i] = *(const bf16x8*)(Bs + rb * 32 + ((l4 * 8) ^ ((((rb & 3) ^ ((rb >> 2) & 3))) << 3)));
    }
#pragma unroll
    for (int i = 0; i < 4; i++)
#pragma unroll
      for (int j = 0; j < 4; j++)
        acc[i][j] = __builtin_amdgcn_mfma_f32_16x16x32_bf16(af[i], bfr[j], acc[i][j], 0, 0, 0);
    __syncthreads();
  }

#pragma unroll
  for (int j = 0; j < 4; j++) {
    const int col = n0 + (wn << 6) + (j << 4) + l15;
    const float bc = bias[col];
#pragma unroll
    for (int i = 0; i < 4; i++) {
#pragma unroll
      for (int r = 0; r < 4; r++) {
        const int row = m0 + (wm << 6) + (i << 4) + (l4 << 2) + r;
        float v = acc[i][j][r] + bc;
        if (mode == 3) {
          int t = row & 2047, b2 = row >> 11;
          out_f[(size_t)(t * 2 + b2) * 1024 + col] = v;
        } else {
          int t = row >> 1, b2 = row & 1, h = col >> 6, dh = col & 63;
          if (mode == 2)
            out_bf[((size_t)(b2 * 16 + h) * 64 + dh) * 2048 + t] = f2bf(v);
          else
            out_bf[((size_t)(b2 * 16 + h) * 2048 + t) * 64 + dh] = f2bf(v);
        }
      }
    }
  }
}

// fused Q/K/V projections: 768 blocks = 3 problems x 256 tiles -> 3 blocks/CU
__global__ __launch_bounds__(256, 3) void gemm_qkv(
    const u16* __restrict__ qbf, const u16* __restrict__ kbf, const u16* __restrict__ vbf,
    const u16* __restrict__ wq, const u16* __restrict__ wk, const u16* __restrict__ wv,
    const float* __restrict__ bq, const float* __restrict__ bk, const float* __restrict__ bv,
    u16* __restrict__ Qh, u16* __restrict__ Kh, u16* __restrict__ Vth) {
  __shared__ u16 As[4096], Bs[4096];
  int wg = blockIdx.x;
  int swz = (wg & 7) * 96 + (wg >> 3);  // 768 % 8 == 0, bijective XCD swizzle
  int prob = swz >> 8, tile = swz & 255;
  if (prob == 0)      gemm_body(qbf, wq, bq, Qh,  nullptr, tile, 0, As, Bs);
  else if (prob == 1) gemm_body(kbf, wk, bk, Kh,  nullptr, tile, 0, As, Bs);
  else                gemm_body(vbf, wv, bv, Vth, nullptr, tile, 2, As, Bs);
}

__global__ __launch_bounds__(256, 3) void gemm_o(
    const u16* __restrict__ ctx, const u16* __restrict__ wo,
    const float* __restrict__ bo, float* __restrict__ out) {
  __shared__ u16 As[4096], Bs[4096];
  int wg = blockIdx.x;
  int swz = (wg & 7) * 32 + (wg >> 3);  // 256 blocks
  gemm_body(ctx, wo, bo, nullptr, out, swz, 3, As, Bs);
}

// ---------------- flash attention ----------------
// 1024 blocks = 32 bh x 32 q-tiles of 64 rows; 4 waves x 16 q-rows each.
// K/V double-buffered in LDS, XOR-swizzled (chunk ^= row&7) via pre-swizzled
// gload_lds source; one barrier per K-tile; prefetch overlaps compute.
__global__ __launch_bounds__(256, 4) void attn_fwd(
    const u16* __restrict__ Qh, const u16* __restrict__ Kh, const u16* __restrict__ Vt,
    const unsigned char* __restrict__ maskb, u16* __restrict__ ctx) {
  __shared__ u16 Ks[2][64 * 64];
  __shared__ u16 Vs[2][64 * 64];
  __shared__ u16 Pl[4][16 * 64];
  const int tid = threadIdx.x, lane = tid & 63, wave = tid >> 6;
  const int wg = blockIdx.x;
  const int swz = (wg & 7) * 128 + (wg >> 3);  // 1024 % 8 == 0
  const int qt = swz & 31, bh = swz >> 5;
  const int bb = bh >> 4, h = bh & 15;
  const int l15 = lane & 15, l4 = lane >> 4;
  const f32x4 zero = {0.f, 0.f, 0.f, 0.f};
  const size_t kvbase = (size_t)bh * 2048 * 64;

  // Q fragments (held in registers for the whole kernel)
  bf16x8 qf[2];
#pragma unroll
  for (int kb = 0; kb < 2; kb++)
    qf[kb] = *(const bf16x8*)(Qh + kvbase + (size_t)(qt * 64 + wave * 16 + l15) * 64 + kb * 32 + l4 * 8);

  f32x4 O[4];
  float m_[4], l_[4];
#pragma unroll
  for (int nd = 0; nd < 4; nd++) O[nd] = zero;
#pragma unroll
  for (int r = 0; r < 4; r++) { m_[r] = -1e30f; l_[r] = 0.f; }

  auto stage = [&](int buf, int kt) {
#pragma unroll
    for (int it = 0; it < 2; ++it) {
      int c = tid + (it << 8);
      int row = c >> 3, qs = (c & 7) ^ (row & 7);
      gload16(Kh + kvbase + (size_t)(kt * 64 + row) * 64 + qs * 8, (void*)(&Ks[buf][c * 8]));
      gload16(Vt + kvbase + (size_t)row * 2048 + kt * 64 + qs * 8, (void*)(&Vs[buf][c * 8]));
    }
  };

  stage(0, 0);
  __syncthreads();

  for (int kt = 0; kt < 32; ++kt) {
    const int cur = kt & 1;
    if (kt < 31) stage(cur ^ 1, kt + 1);

    // --- S = Q K^T ---
    bf16x8 kf[4][2];
#pragma unroll
    for (int ni = 0; ni < 4; ni++) {
      int row = ni * 16 + l15;
#pragma unroll
      for (int kb = 0; kb < 2; kb++)
        kf[ni][kb] = *(const bf16x8*)(&Ks[cur][row * 64 + (((kb * 64 + l4 * 16) ^ ((row & 7) << 4)) >> 1)]);
    }
    f32x4 s[4];
#pragma unroll
    for (int ni = 0; ni < 4; ni++) s[ni] = zero;
    __builtin_amdgcn_s_setprio(1);
#pragma unroll
    for (int ni = 0; ni < 4; ni++)
#pragma unroll
      for (int kb = 0; kb < 2; kb++)
        s[ni] = __builtin_amdgcn_mfma_f32_16x16x32_bf16(qf[kb], kf[ni][kb], s[ni], 0, 0, 0);
    __builtin_amdgcn_s_setprio(0);

    // --- scale + key-padding mask ---
    float msk[4];
#pragma unroll
    for (int ni = 0; ni < 4; ni++)
      msk[ni] = maskb[bb * 2048 + kt * 64 + ni * 16 + l15] ? -3.0e38f : 0.0f;
#pragma unroll
    for (int ni = 0; ni < 4; ni++)
#pragma unroll
      for (int r = 0; r < 4; r++)
        s[ni][r] = s[ni][r] * 0.125f + msk[ni];

    // --- online softmax (rows = l4*4+r over 16 l15 lanes) ---
    float pm[4];
#pragma unroll
    for (int r = 0; r < 4; r++)
      pm[r] = fmaxf(fmaxf(s[0][r], s[1][r]), fmaxf(s[2][r], s[3][r]));
#pragma unroll
    for (int off = 1; off < 16; off <<= 1)
#pragma unroll
      for (int r = 0; r < 4; r++) pm[r] = fmaxf(pm[r], __shfl_xor(pm[r], off));
    float al[4];
#pragma unroll
    for (int r = 0; r < 4; r++) {
      float mn = fmaxf(m_[r], pm[r]);
      al[r] = __expf(m_[r] - mn);
      m_[r] = mn;
    }
    float rs[4] = {0.f, 0.f, 0.f, 0.f};
#pragma unroll
    for (int ni = 0; ni < 4; ni++)
#pragma unroll
      for (int r = 0; r < 4; r++) {
        float p = __expf(s[ni][r] - m_[r]);
        s[ni][r] = p;
        rs[r] += p;
      }
#pragma unroll
    for (int off = 1; off < 16; off <<= 1)
#pragma unroll
      for (int r = 0; r < 4; r++) rs[r] += __shfl_xor(rs[r], off);
#pragma unroll
    for (int r = 0; r < 4; r++) l_[r] = l_[r] * al[r] + rs[r];
#pragma unroll
    for (int nd = 0; nd < 4; nd++)
#pragma unroll
      for (int r = 0; r < 4; r++) O[nd][r] *= al[r];

    // --- P -> LDS (bf16, swizzled rows) ---
#pragma unroll
    for (int ni = 0; ni < 4; ni++)
#pragma unroll
      for (int r = 0; r < 4; r++) {
        int row = l4 * 4 + r;
        Pl[wave][row * 64 + ((16 * ni + l15) ^ ((row & 7) << 3))] = f2bf(s[ni][r]);
      }

    // --- O += P V ---
    bf16x8 pa[2], vf[4][2];
#pragma unroll
    for (int jb = 0; jb < 2; jb++)
      pa[jb] = *(const bf16x8*)(&Pl[wave][l15 * 64 + ((jb * 32 + l4 * 8) ^ ((l15 & 7) << 3))]);
#pragma unroll
    for (int nd = 0; nd < 4; nd++) {
      int row = nd * 16 + l15;
#pragma unroll
      for (int jb = 0; jb < 2; jb++)
        vf[nd][jb] = *(const bf16x8*)(&Vs[cur][row * 64 + (((jb * 64 + l4 * 16) ^ ((row & 7) << 4)) >> 1)]);
    }
    __builtin_amdgcn_s_setprio(1);
#pragma unroll
    for (int nd = 0; nd < 4; nd++)
#pragma unroll
      for (int jb = 0; jb < 2; jb++)
        O[nd] = __builtin_amdgcn_mfma_f32_16x16x32_bf16(pa[jb], vf[nd][jb], O[nd], 0, 0, 0);
    __builtin_amdgcn_s_setprio(0);

    __syncthreads();  // prefetch landed + all reads of cur done
  }

  // --- normalize + write ctx[b][t][h*64+d] ---
#pragma unroll
  for (int r = 0; r < 4; r++) {
    float li = l_[r];
    float inv = (li > 0.f) ? 1.0f / li : 0.f;
    int t = qt * 64 + wave * 16 + l4 * 4 + r;
#pragma unroll
    for (int nd = 0; nd < 4; nd++) {
      int d = nd * 16 + l15;
      ctx[((size_t)bb * 2048 + t) * 1024 + h * 64 + d] = f2bf(O[nd][r] * inv);
    }
  }
}

// ---------------- host ----------------
extern "C" void kernel_launch(void* const* d_in, const int* in_sizes, int n_in,
                              void* d_out, int out_size, void* d_ws, size_t ws_size,
                              hipStream_t stream) {
  const float* q_in = (const float*)d_in[0];
  const float* k_in = (const float*)d_in[1];
  const float* v_in = (const float*)d_in[2];
  const float* Wq = (const float*)d_in[3];
  const float* bq = (const float*)d_in[4];
  const float* Wk = (const float*)d_in[5];
  const float* bk = (const float*)d_in[6];
  const float* Wv = (const float*)d_in[7];
  const float* bv = (const float*)d_in[8];
  const float* Wo = (const float*)d_in[9];
  const float* bo = (const float*)d_in[10];
  const void* mask = d_in[11];

  const size_t SZ_X = (size_t)4194304 * 2;  // T*B*C bf16 bytes
  const size_t SZ_W = (size_t)1048576 * 2;  // C*C bf16 bytes
  uint8_t* ws = (uint8_t*)d_ws;
  unsigned char* mb = ws + 0;
  size_t off = 8192;
  u16* qbf = (u16*)(ws + off); off += SZ_X;   // contiguous convert dest begins here
  u16* kbf = (u16*)(ws + off); off += SZ_X;
  u16* vbf = (u16*)(ws + off); off += SZ_X;
  u16* wqb = (u16*)(ws + off); off += SZ_W;
  u16* wkb = (u16*)(ws + off); off += SZ_W;
  u16* wvb = (u16*)(ws + off); off += SZ_W;
  u16* wob = (u16*)(ws + off); off += SZ_W;
  u16* Qh  = (u16*)(ws + off); off += SZ_X;
  u16* Kh  = (u16*)(ws + off); off += SZ_X;
  u16* Vth = (u16*)(ws + off); off += SZ_X;
  u16* ctx = (u16*)(ws + off); off += SZ_X;
  if (ws_size < off) return;

  mask_prep<<<1, 1024, 0, stream>>>((const u32*)mask, mb);
  cvt_all<<<16384, 256, 0, stream>>>(q_in, k_in, v_in, Wq, Wk, Wv, Wo, (ushort4*)qbf);

  gemm_qkv<<<768, 256, 0, stream>>>(qbf, kbf, vbf, wqb, wkb, wvb, bq, bk, bv, Qh, Kh, Vth);

  attn_fwd<<<1024, 256, 0, stream>>>(Qh, Kh, Vth, mb, ctx);

  gemm_o<<<256, 256, 0, stream>>>(ctx, wob, bo, (float*)d_out);
}

// Round 3
// 151.941 us; speedup vs baseline: 2.1750x; 1.2707x over previous
//
#include <hip/hip_runtime.h>
#include <stdint.h>

typedef __attribute__((ext_vector_type(4))) float f32x4;
typedef __attribute__((ext_vector_type(8))) short bf16x8;
typedef __attribute__((ext_vector_type(2))) unsigned int u32x2;
typedef unsigned short u16;
typedef unsigned int u32;

#define DEVINL __device__ __forceinline__

DEVINL u16 f2bf(float f) {
  u32 u = __builtin_bit_cast(u32, f);
  u += 0x7FFFu + ((u >> 16) & 1u);
  return (u16)(u >> 16);
}

DEVINL float exp2_hw(float x) {
  float r;
  asm("v_exp_f32 %0, %1\n\ts_nop 0" : "=v"(r) : "v"(x));
  return r;
}

DEVINL u32 cvt_pk_bf16(float lo, float hi) {
  u32 r;
  asm("v_cvt_pk_bf16_f32 %0, %1, %2" : "=v"(r) : "v"(lo), "v"(hi));
  return r;
}

DEVINL void gload16(const void* g, void* l) {
  __builtin_amdgcn_global_load_lds((const __attribute__((address_space(1))) void*)g,
                                   (__attribute__((address_space(3))) void*)l, 16, 0, 0);
}

// ---------------- fused fp32 -> bf16 convert (q,k,v,Wq,Wk,Wv,Wo) ----------------
__global__ void cvt_all(const float* __restrict__ q, const float* __restrict__ k,
                        const float* __restrict__ v, const float* __restrict__ wq,
                        const float* __restrict__ wk, const float* __restrict__ wv,
                        const float* __restrict__ wo, ushort4* __restrict__ dst) {
  int i = blockIdx.x * 256 + threadIdx.x;  // float4 index, total 4194304
  float4 v4;
  if (i < 1048576) v4 = ((const float4*)q)[i];
  else if (i < 2097152) v4 = ((const float4*)k)[i - 1048576];
  else if (i < 3145728) v4 = ((const float4*)v)[i - 2097152];
  else {
    int j = i - 3145728;
    if (j < 262144) v4 = ((const float4*)wq)[j];
    else if (j < 524288) v4 = ((const float4*)wk)[j - 262144];
    else if (j < 786432) v4 = ((const float4*)wv)[j - 524288];
    else v4 = ((const float4*)wo)[j - 786432];
  }
  ushort4 o;
  o.x = f2bf(v4.x); o.y = f2bf(v4.y); o.z = f2bf(v4.z); o.w = f2bf(v4.w);
  dst[i] = o;
}

// ---------------- mask detect + canonicalize to additive f32 (log2 domain) ----------------
__global__ void mask_prep(const u32* __restrict__ mraw, float* __restrict__ mout) {
  __shared__ int notint, notfloat;
  int tid = threadIdx.x;
  if (tid == 0) { notint = 0; notfloat = 0; }
  __syncthreads();
  u32 w = mraw[tid];
  if (w != 0u && w != 1u) notint = 1;
  if (w != 0u && w != 0x3f800000u) notfloat = 1;
  __syncthreads();
  bool words = (!notint) || (!notfloat);
  for (int i = tid; i < 4096; i += 1024) {
    u32 v = words ? mraw[i] : (u32)(((const unsigned char*)mraw)[i]);
    mout[i] = v ? -1.0e38f : 0.0f;
  }
}

// ---------------- bf16 GEMM body, Y = A(4096xK) * W(1024xK)^T + bias ----------------
DEVINL void gemm_body(const u16* __restrict__ A, const u16* __restrict__ W,
                      const float* __restrict__ bias, u16* __restrict__ out_bf,
                      float* __restrict__ out_f, int tile, int mode,
                      u16* As, u16* Bs) {
  const int tid = threadIdx.x, lane = tid & 63;
  const int wave = tid >> 6, wm = wave & 1, wn = wave >> 1;
  const int m0 = (tile >> 3) << 7;  // tiles_n = 8
  const int n0 = (tile & 7) << 7;
  const int l15 = lane & 15, l4 = lane >> 4;
  const int K = 1024;
  const f32x4 zero = {0.f, 0.f, 0.f, 0.f};
  f32x4 acc[4][4];
#pragma unroll
  for (int i = 0; i < 4; i++)
#pragma unroll
    for (int j = 0; j < 4; j++) acc[i][j] = zero;

  for (int kt = 0; kt < 1024; kt += 32) {
#pragma unroll
    for (int it = 0; it < 2; ++it) {
      int c = tid + (it << 8);
      int row = c >> 2, qs = (c & 3) ^ ((row & 3) ^ ((row >> 2) & 3));
      gload16(A + (size_t)(m0 + row) * K + kt + qs * 8, (void*)(As + c * 8));
      gload16(W + (size_t)(n0 + row) * K + kt + qs * 8, (void*)(Bs + c * 8));
    }
    __syncthreads();
    bf16x8 af[4], bfr[4];
#pragma unroll
    for (int i = 0; i < 4; i++) {
      int ra = (wm << 6) + (i << 4) + l15;
      int rb = (wn << 6) + (i << 4) + l15;
      af[i]  = *(const bf16x8*)(As + ra * 32 + ((l4 * 8) ^ ((((ra & 3) ^ ((ra >> 2) & 3))) << 3)));
      bfr[i] = *(const bf16x8*)(Bs + rb * 32 + ((l4 * 8) ^ ((((rb & 3) ^ ((rb >> 2) & 3))) << 3)));
    }
#pragma unroll
    for (int i = 0; i < 4; i++)
#pragma unroll
      for (int j = 0; j < 4; j++)
        acc[i][j] = __builtin_amdgcn_mfma_f32_16x16x32_bf16(af[i], bfr[j], acc[i][j], 0, 0, 0);
    __syncthreads();
  }

#pragma unroll
  for (int j = 0; j < 4; j++) {
    const int col = n0 + (wn << 6) + (j << 4) + l15;
    const float bc = bias[col];
#pragma unroll
    for (int i = 0; i < 4; i++) {
#pragma unroll
      for (int r = 0; r < 4; r++) {
        const int row = m0 + (wm << 6) + (i << 4) + (l4 << 2) + r;
        float v = acc[i][j][r] + bc;
        if (mode == 3) {
          int t = row & 2047, b2 = row >> 11;
          out_f[(size_t)(t * 2 + b2) * 1024 + col] = v;
        } else {
          int t = row >> 1, b2 = row & 1, h = col >> 6, dh = col & 63;
          if (mode == 2)
            out_bf[((size_t)(b2 * 16 + h) * 64 + dh) * 2048 + t] = f2bf(v);
          else
            out_bf[((size_t)(b2 * 16 + h) * 2048 + t) * 64 + dh] = f2bf(v);
        }
      }
    }
  }
}

__global__ __launch_bounds__(256, 3) void gemm_qkv(
    const u16* __restrict__ qbf, const u16* __restrict__ kbf, const u16* __restrict__ vbf,
    const u16* __restrict__ wq, const u16* __restrict__ wk, const u16* __restrict__ wv,
    const float* __restrict__ bq, const float* __restrict__ bk, const float* __restrict__ bv,
    u16* __restrict__ Qh, u16* __restrict__ Kh, u16* __restrict__ Vth) {
  __shared__ u16 As[4096], Bs[4096];
  int wg = blockIdx.x;
  int swz = (wg & 7) * 96 + (wg >> 3);
  int prob = swz >> 8, tile = swz & 255;
  if (prob == 0)      gemm_body(qbf, wq, bq, Qh,  nullptr, tile, 0, As, Bs);
  else if (prob == 1) gemm_body(kbf, wk, bk, Kh,  nullptr, tile, 0, As, Bs);
  else                gemm_body(vbf, wv, bv, Vth, nullptr, tile, 2, As, Bs);
}

__global__ __launch_bounds__(256, 3) void gemm_o(
    const u16* __restrict__ ctx, const u16* __restrict__ wo,
    const float* __restrict__ bo, float* __restrict__ out) {
  __shared__ u16 As[4096], Bs[4096];
  int wg = blockIdx.x;
  int swz = (wg & 7) * 32 + (wg >> 3);
  gemm_body(ctx, wo, bo, nullptr, out, swz, 3, As, Bs);
}

// ---------------- flash attention (swapped-operand, in-register softmax) ----------------
// 1024 blocks = 32 bh x 32 q-tiles of 64; 4 waves x 16 q each (q = l15).
// S^T = mfma(Kfrag, Qfrag): col=q(l15), row=key(l4*4+r) -> row reductions are
// per-lane over 16 regs + 2 shfl_xor. O^T = mfma(Vtfrag, Pfrag): col=q, row=d.
// All softmax in exp2 domain; defer-max (THR=8) skips O-rescale on most tiles.
__global__ __launch_bounds__(256, 4) void attn_fwd(
    const u16* __restrict__ Qh, const u16* __restrict__ Kh, const u16* __restrict__ Vt,
    const float* __restrict__ maskf, u16* __restrict__ ctx) {
  __shared__ u16 Ks[2][64 * 64];
  __shared__ u16 Vs[2][64 * 64];
  __shared__ u32 Plu[4][16 * 32];  // per-wave packed P: [q][key/2], XOR-swizzled
  const int tid = threadIdx.x, lane = tid & 63, wave = tid >> 6;
  const int wg = blockIdx.x;
  const int swz = (wg & 7) * 128 + (wg >> 3);
  const int qt = swz & 31, bh = swz >> 5;
  const int bb = bh >> 4, h = bh & 15;
  const int l15 = lane & 15, l4 = lane >> 4;
  const f32x4 zero = {0.f, 0.f, 0.f, 0.f};
  const size_t kvbase = (size_t)bh * 2048 * 64;
  const float C2 = 0.18033688011112042f;  // 0.125 * log2(e)

  // Q fragments: B-frag rows = q = l15
  bf16x8 qf[2];
#pragma unroll
  for (int kb = 0; kb < 2; kb++)
    qf[kb] = *(const bf16x8*)(Qh + kvbase + (size_t)(qt * 64 + wave * 16 + l15) * 64 + kb * 32 + l4 * 8);

  f32x4 O[4];  // O^T fragments: lane holds O[q=l15][d = nd*16 + l4*4 + r]
#pragma unroll
  for (int nd = 0; nd < 4; nd++) O[nd] = zero;
  float m_ = -1.0e30f, l_ = 0.f;

  auto stage = [&](int buf, int kt) {
#pragma unroll
    for (int it = 0; it < 2; ++it) {
      int c = tid + (it << 8);
      int row = c >> 3, qs = (c & 7) ^ (row & 7);
      gload16(Kh + kvbase + (size_t)(kt * 64 + row) * 64 + qs * 8, (void*)(&Ks[buf][c * 8]));
      gload16(Vt + kvbase + (size_t)row * 2048 + kt * 64 + qs * 8, (void*)(&Vs[buf][c * 8]));
    }
  };

  stage(0, 0);
  __syncthreads();

  const float4* mrow = (const float4*)(maskf + bb * 2048);

  for (int kt = 0; kt < 32; ++kt) {
    const int cur = kt & 1;
    if (kt < 31) stage(cur ^ 1, kt + 1);

    // --- S^T = K Q^T : s[ni] rows = keys ni*16 + l4*4 + r, col = q = l15 ---
    f32x4 s[4];
    __builtin_amdgcn_s_setprio(1);
#pragma unroll
    for (int ni = 0; ni < 4; ni++) {
      int row = ni * 16 + l15;
      s[ni] = zero;
#pragma unroll
      for (int kb = 0; kb < 2; kb++) {
        bf16x8 kf = *(const bf16x8*)(&Ks[cur][row * 64 + (((kb * 64 + l4 * 16) ^ ((row & 7) << 4)) >> 1)]);
        s[ni] = __builtin_amdgcn_mfma_f32_16x16x32_bf16(kf, qf[kb], s[ni], 0, 0, 0);
      }
    }
    __builtin_amdgcn_s_setprio(0);

    // --- scale (log2 domain) + additive mask (uniform over l15) ---
#pragma unroll
    for (int ni = 0; ni < 4; ni++) {
      float4 mv = mrow[(kt * 16) + ni * 4 + l4];  // keys ni*16 + l4*4 + r
      s[ni][0] = s[ni][0] * C2 + mv.x;
      s[ni][1] = s[ni][1] * C2 + mv.y;
      s[ni][2] = s[ni][2] * C2 + mv.z;
      s[ni][3] = s[ni][3] * C2 + mv.w;
    }

    // --- per-lane max over 16 regs + 2 shfl ---
    float pm0 = fmaxf(fmaxf(s[0][0], s[0][1]), fmaxf(s[0][2], s[0][3]));
    float pm1 = fmaxf(fmaxf(s[1][0], s[1][1]), fmaxf(s[1][2], s[1][3]));
    float pm2 = fmaxf(fmaxf(s[2][0], s[2][1]), fmaxf(s[2][2], s[2][3]));
    float pm3 = fmaxf(fmaxf(s[3][0], s[3][1]), fmaxf(s[3][2], s[3][3]));
    float pm = fmaxf(fmaxf(pm0, pm1), fmaxf(pm2, pm3));
    pm = fmaxf(pm, __shfl_xor(pm, 16));
    pm = fmaxf(pm, __shfl_xor(pm, 32));

    // --- defer-max: only rescale when the running max grows past THR ---
    if (__any(pm > m_ + 8.f)) {
      float mn = fmaxf(m_, pm);
      float al = exp2_hw(m_ - mn);
      m_ = mn;
      l_ *= al;
#pragma unroll
      for (int nd = 0; nd < 4; nd++)
#pragma unroll
        for (int r = 0; r < 4; r++) O[nd][r] *= al;
    }

    // --- P = exp2(S - m), row-sum ---
    float rs = 0.f;
#pragma unroll
    for (int ni = 0; ni < 4; ni++) {
#pragma unroll
      for (int r = 0; r < 4; r++) {
        float p = exp2_hw(s[ni][r] - m_);
        s[ni][r] = p;
        rs += p;
      }
    }
    rs += __shfl_xor(rs, 16);
    rs += __shfl_xor(rs, 32);
    l_ += rs;

    // --- pack P to bf16 pairs, store to per-wave LDS (swizzled u32 cols) ---
#pragma unroll
    for (int ni = 0; ni < 4; ni++) {
      u32x2 w;
      w.x = cvt_pk_bf16(s[ni][0], s[ni][1]);
      w.y = cvt_pk_bf16(s[ni][2], s[ni][3]);
      int col = ni * 8 + l4 * 2;
      *(u32x2*)(&Plu[wave][l15 * 32 + (col ^ ((l15 & 7) << 2))]) = w;
    }

    // --- O^T += V^T P : A = Vt rows d, B = P rows q ---
    bf16x8 pb[2];
#pragma unroll
    for (int kb = 0; kb < 2; kb++) {
      int rcol = kb * 16 + l4 * 4;
      pb[kb] = *(const bf16x8*)(&Plu[wave][l15 * 32 + (rcol ^ ((l15 & 7) << 2))]);
    }
    __builtin_amdgcn_s_setprio(1);
#pragma unroll
    for (int nd = 0; nd < 4; nd++) {
      int row = nd * 16 + l15;
#pragma unroll
      for (int jb = 0; jb < 2; jb++) {
        bf16x8 vf = *(const bf16x8*)(&Vs[cur][row * 64 + (((jb * 64 + l4 * 16) ^ ((row & 7) << 4)) >> 1)]);
        O[nd] = __builtin_amdgcn_mfma_f32_16x16x32_bf16(vf, pb[jb], O[nd], 0, 0, 0);
      }
    }
    __builtin_amdgcn_s_setprio(0);

    __syncthreads();
  }

  // --- normalize + write ctx[b][t][h*64+d], 8B packed stores ---
  float inv = (l_ > 0.f) ? 1.0f / l_ : 0.f;
  int t = qt * 64 + wave * 16 + l15;
  u16* cbase = ctx + ((size_t)bb * 2048 + t) * 1024 + h * 64;
#pragma unroll
  for (int nd = 0; nd < 4; nd++) {
    u32x2 w;
    w.x = cvt_pk_bf16(O[nd][0] * inv, O[nd][1] * inv);
    w.y = cvt_pk_bf16(O[nd][2] * inv, O[nd][3] * inv);
    *(u32x2*)(cbase + nd * 16 + l4 * 4) = w;
  }
}

// ---------------- host ----------------
extern "C" void kernel_launch(void* const* d_in, const int* in_sizes, int n_in,
                              void* d_out, int out_size, void* d_ws, size_t ws_size,
                              hipStream_t stream) {
  const float* q_in = (const float*)d_in[0];
  const float* k_in = (const float*)d_in[1];
  const float* v_in = (const float*)d_in[2];
  const float* Wq = (const float*)d_in[3];
  const float* bq = (const float*)d_in[4];
  const float* Wk = (const float*)d_in[5];
  const float* bk = (const float*)d_in[6];
  const float* Wv = (const float*)d_in[7];
  const float* bv = (const float*)d_in[8];
  const float* Wo = (const float*)d_in[9];
  const float* bo = (const float*)d_in[10];
  const void* mask = d_in[11];

  const size_t SZ_X = (size_t)4194304 * 2;  // T*B*C bf16 bytes
  const size_t SZ_W = (size_t)1048576 * 2;  // C*C bf16 bytes
  uint8_t* ws = (uint8_t*)d_ws;
  float* mf = (float*)ws;                    // 4096 floats = 16 KB
  size_t off = 32768;
  u16* qbf = (u16*)(ws + off); off += SZ_X;  // contiguous convert dest begins here
  u16* kbf = (u16*)(ws + off); off += SZ_X;
  u16* vbf = (u16*)(ws + off); off += SZ_X;
  u16* wqb = (u16*)(ws + off); off += SZ_W;
  u16* wkb = (u16*)(ws + off); off += SZ_W;
  u16* wvb = (u16*)(ws + off); off += SZ_W;
  u16* wob = (u16*)(ws + off); off += SZ_W;
  u16* Qh  = (u16*)(ws + off); off += SZ_X;
  u16* Kh  = (u16*)(ws + off); off += SZ_X;
  u16* Vth = (u16*)(ws + off); off += SZ_X;
  u16* ctx = (u16*)(ws + off); off += SZ_X;
  if (ws_size < off) return;

  mask_prep<<<1, 1024, 0, stream>>>((const u32*)mask, mf);
  cvt_all<<<16384, 256, 0, stream>>>(q_in, k_in, v_in, Wq, Wk, Wv, Wo, (ushort4*)qbf);

  gemm_qkv<<<768, 256, 0, stream>>>(qbf, kbf, vbf, wqb, wkb, wvb, bq, bk, bv, Qh, Kh, Vth);

  attn_fwd<<<1024, 256, 0, stream>>>(Qh, Kh, Vth, mf, ctx);

  gemm_o<<<256, 256, 0, stream>>>(ctx, wob, bo, (float*)d_out);
}